// Round 1
// 508.414 us; speedup vs baseline: 1.2093x; 1.2093x over previous
//
#include <hip/hip_runtime.h>

typedef __bf16 bf16x8 __attribute__((ext_vector_type(8)));
typedef float  f32x4  __attribute__((ext_vector_type(4)));
typedef unsigned short u16x8 __attribute__((ext_vector_type(8)));

__device__ __forceinline__ float b2f(unsigned short u) {
    unsigned int x = ((unsigned int)u) << 16;
    float f; __builtin_memcpy(&f, &x, 4); return f;
}
__device__ __forceinline__ unsigned short f2b(float f) {
    unsigned int x; __builtin_memcpy(&x, &f, 4);
    unsigned int r = (x + 0x7FFFu + ((x >> 16) & 1u)) >> 16;
    return (unsigned short)r;
}
__device__ __forceinline__ void async16(void* lds, const void* g) {
    __builtin_amdgcn_global_load_lds((const __attribute__((address_space(1))) void*)g,
                                     (__attribute__((address_space(3))) void*)lds, 16, 0, 0);
}

// ---------------------------------------------------------------------------
// K1: LN(m) -> v = mhat@Wv.T (bf16, per-head transposed layout vT[h][c=n*8+d][j])
//              g = sigmoid(mhat@Wg.T) (bf16, standard layout g[(i*512+n)*64+h*8+d])
// block = (n, s-chunk of 32); 4 waves.
// Phase 1: cooperative vectorized LN of all 32 rows -> mh in LDS.
// Phase 2: wave 0/1 = v matmul (rows 0-15 / 16-31), wave 2/3 = g matmul.
//          Each thread holds only 64 weight floats (vs 128 before) -> no
//          rematerialization / spill of the weight array.
// ---------------------------------------------------------------------------
__global__ __launch_bounds__(256) void k1_ln_vg(
    const float* __restrict__ m, const float* __restrict__ lnw, const float* __restrict__ lnb,
    const float* __restrict__ Wv, const float* __restrict__ Wg,
    unsigned short* __restrict__ vT, unsigned short* __restrict__ gB)
{
    __shared__ float mh[32][68];      // pad 64->68 so phase-1 row writes spread banks
    __shared__ float vstage[32][65];
    const int t = threadIdx.x, w = t >> 6, lane = t & 63;
    const int n = blockIdx.x;
    const int s0 = blockIdx.y * 32;

    // phase-2 operand: this wave's matrix (0,1 -> Wv ; 2,3 -> Wg), column = lane.
    const int mat = w >> 1, half = w & 1;
    const float* __restrict__ Wm = mat ? Wg : Wv;
    float wt[64];
#pragma unroll
    for (int q = 0; q < 16; q++) {
        float4 a = *(const float4*)&Wm[lane * 64 + q * 4];
        wt[4*q+0]=a.x; wt[4*q+1]=a.y; wt[4*q+2]=a.z; wt[4*q+3]=a.w;
    }

    // ---- phase 1: LN of 32 rows. thread = (row = t>>3, 8-c chunk = t&7) ----
    {
        const int rl = t >> 3;            // 0..31
        const int c  = (t & 7) * 8;
        const int s  = s0 + rl;
        const float* src = &m[((size_t)s * 512 + n) * 64 + c];
        float4 x0 = *(const float4*)src;
        float4 x1 = *(const float4*)(src + 4);
        float sum = x0.x+x0.y+x0.z+x0.w + x1.x+x1.y+x1.z+x1.w;
        float sq  = x0.x*x0.x+x0.y*x0.y+x0.z*x0.z+x0.w*x0.w
                  + x1.x*x1.x+x1.y*x1.y+x1.z*x1.z+x1.w*x1.w;
#pragma unroll
        for (int msk = 4; msk; msk >>= 1) { sum += __shfl_xor(sum, msk); sq += __shfl_xor(sq, msk); }
        float mu  = sum * (1.f / 64.f);
        float var = sq * (1.f / 64.f) - mu * mu;
        float rs  = rsqrtf(var + 1e-5f);
        float4 lw0 = *(const float4*)&lnw[c], lw1 = *(const float4*)&lnw[c + 4];
        float4 lb0 = *(const float4*)&lnb[c], lb1 = *(const float4*)&lnb[c + 4];
        float4 h0, h1;
        h0.x = (x0.x - mu) * rs * lw0.x + lb0.x;
        h0.y = (x0.y - mu) * rs * lw0.y + lb0.y;
        h0.z = (x0.z - mu) * rs * lw0.z + lb0.z;
        h0.w = (x0.w - mu) * rs * lw0.w + lb0.w;
        h1.x = (x1.x - mu) * rs * lw1.x + lb1.x;
        h1.y = (x1.y - mu) * rs * lw1.y + lb1.y;
        h1.z = (x1.z - mu) * rs * lw1.z + lb1.z;
        h1.w = (x1.w - mu) * rs * lw1.w + lb1.w;
        *(float4*)&mh[rl][c]     = h0;
        *(float4*)&mh[rl][c + 4] = h1;
    }
    __syncthreads();

    // ---- phase 2: 16 rows per wave, lane = output column ----
    const int rbase = half * 16;
#pragma unroll 4
    for (int r = 0; r < 16; r++) {
        const int rl = rbase + r;
        float acc = 0.f;
#pragma unroll
        for (int q = 0; q < 16; q++) {
            float4 mm = *(const float4*)&mh[rl][q * 4];   // wave-uniform broadcast
            acc += mm.x*wt[4*q] + mm.y*wt[4*q+1] + mm.z*wt[4*q+2] + mm.w*wt[4*q+3];
        }
        if (mat == 0) {
            vstage[rl][lane] = acc;
        } else {
            float gg = 1.f / (1.f + __expf(-acc));
            gB[((size_t)(s0 + rl) * 512 + n) * 64 + lane] = f2b(gg);
        }
    }
    __syncthreads();

    // transpose-write v: thread t -> (h = t>>5, d = (t>>2)&7, jc = t&3), 8 j's contiguous
    const int h = t >> 5, d = (t >> 2) & 7, jc = t & 3;
    u16x8 pk;
#pragma unroll
    for (int u = 0; u < 8; u++) pk[u] = f2b(vstage[jc * 8 + u][h * 8 + d]);
    size_t off = (size_t)h * 2097152 + (size_t)(n * 8 + d) * 512 + (size_t)(s0 + jc * 8);
    *(u16x8*)(vT + off) = pk;
}

// ---------------------------------------------------------------------------
// K2: LN(z) row (128) -> logits b[i][j][h] fp32.  wave per row; W_b in regs
// lane = (h = lane&7, cg = lane>>3): partial dot over 16 c's, xor-reduce 8/16/32.
// ---------------------------------------------------------------------------
__global__ __launch_bounds__(256) void k2_ln_b(
    const float* __restrict__ z, const float* __restrict__ lnw, const float* __restrict__ lnb,
    const float* __restrict__ Wb, float* __restrict__ bL)
{
    __shared__ float zrow[4][132];
    const int t = threadIdx.x, w = t >> 6, lane = t & 63;
    const int h = lane & 7, cg = lane >> 3;
    float wb[16];
#pragma unroll
    for (int q = 0; q < 4; q++) {
        float4 a = *(const float4*)&Wb[h * 128 + cg * 16 + q * 4];
        wb[4*q+0]=a.x; wb[4*q+1]=a.y; wb[4*q+2]=a.z; wb[4*q+3]=a.w;
    }
    const float lw0 = lnw[lane], lw1 = lnw[64 + lane];
    const float lb0 = lnb[lane], lb1 = lnb[64 + lane];
    const int nw = gridDim.x * 4;
    for (int row = blockIdx.x * 4 + w; row < 262144; row += nw) {
        float x0 = z[(size_t)row * 128 + lane];
        float x1 = z[(size_t)row * 128 + 64 + lane];
        float sum = x0 + x1, sq = x0 * x0 + x1 * x1;
#pragma unroll
        for (int msk = 32; msk; msk >>= 1) { sum += __shfl_xor(sum, msk); sq += __shfl_xor(sq, msk); }
        float mu = sum * (1.f / 128.f);
        float var = sq * (1.f / 128.f) - mu * mu;
        float rs = rsqrtf(var + 1e-5f);
        zrow[w][lane]      = (x0 - mu) * rs * lw0 + lb0;
        zrow[w][64 + lane] = (x1 - mu) * rs * lw1 + lb1;
        float acc = 0.f;
#pragma unroll
        for (int q = 0; q < 4; q++) {
            float4 zz = *(float4*)&zrow[w][cg * 16 + q * 4];
            acc += zz.x*wb[4*q] + zz.y*wb[4*q+1] + zz.z*wb[4*q+2] + zz.w*wb[4*q+3];
        }
#pragma unroll
        for (int msk = 8; msk < 64; msk <<= 1) acc += __shfl_xor(acc, msk);
        if (lane < 8) bL[(size_t)row * 8 + lane] = acc;
    }
}

// ---------------------------------------------------------------------------
// K3: softmax over j per (i,h); reads b[i][j][h], writes w bf16 planar wp[h][i][j].
// block per i; 32-thread group per h.
// ---------------------------------------------------------------------------
__global__ __launch_bounds__(256) void k3_softmax(
    const float* __restrict__ bL, unsigned short* __restrict__ wp)
{
    __shared__ float bl[8][520];
    const int t = threadIdx.x;
    const int i = blockIdx.x;
    const float* src = bL + (size_t)i * 4096;
#pragma unroll
    for (int q = 0; q < 4; q++) {
        float4 a = *(const float4*)&src[q * 1024 + t * 4];
        int idx = q * 1024 + t * 4;
        bl[(idx+0)&7][(idx+0)>>3] = a.x;
        bl[(idx+1)&7][(idx+1)>>3] = a.y;
        bl[(idx+2)&7][(idx+2)>>3] = a.z;
        bl[(idx+3)&7][(idx+3)>>3] = a.w;
    }
    __syncthreads();
    const int h = t >> 5, l32 = t & 31;
    float vals[16];
    float mx = -1e30f;
#pragma unroll
    for (int jj = 0; jj < 16; jj++) { vals[jj] = bl[h][l32 + 32 * jj]; mx = fmaxf(mx, vals[jj]); }
#pragma unroll
    for (int msk = 1; msk < 32; msk <<= 1) mx = fmaxf(mx, __shfl_xor(mx, msk, 32));
    float s = 0.f;
#pragma unroll
    for (int jj = 0; jj < 16; jj++) { vals[jj] = __expf(vals[jj] - mx); s += vals[jj]; }
#pragma unroll
    for (int msk = 1; msk < 32; msk <<= 1) s += __shfl_xor(s, msk, 32);
    const float inv = 1.f / s;
    unsigned short* dst = wp + (size_t)h * 262144 + (size_t)i * 512;
#pragma unroll
    for (int jj = 0; jj < 16; jj++) dst[l32 + 32 * jj] = f2b(vals[jj] * inv);
}

// ---------------------------------------------------------------------------
// K4: per-head GEMM o_h[i][c] = w_h[i][:] @ vT_h[c][:]^T  (K=j=512), bf16 MFMA
// 128x128 tile, 4 waves, 16x16x32 frags; epilogue fuses g-gate, writes go bf16.
// ---------------------------------------------------------------------------
__global__ __launch_bounds__(256) void k4_einsum(
    const unsigned short* __restrict__ wp, const unsigned short* __restrict__ vT,
    const unsigned short* __restrict__ gB, unsigned short* __restrict__ go)
{
    __shared__ __align__(16) unsigned short As[128 * 32];
    __shared__ __align__(16) unsigned short Bs[128 * 32];
    const int t = threadIdx.x;
    const int c0 = blockIdx.x * 128, i0 = blockIdx.y * 128, h = blockIdx.z;
    const unsigned short* Ab = wp + (size_t)h * 262144;
    const unsigned short* Bb = vT + (size_t)h * 2097152;
    const int w = t >> 6, lane = t & 63, quad = lane >> 4, lq = lane & 15;
    const int wi = w >> 1, wc = w & 1;

    f32x4 zero = {0.f, 0.f, 0.f, 0.f};
    f32x4 acc[4][4];
#pragma unroll
    for (int mi = 0; mi < 4; mi++)
#pragma unroll
        for (int ni = 0; ni < 4; ni++) acc[mi][ni] = zero;

    for (int k0 = 0; k0 < 512; k0 += 32) {
#pragma unroll
        for (int r = 0; r < 2; r++) {
            int idx = r * 256 + t;
            int row = idx >> 2, q = idx & 3;
            async16(&As[idx * 8], Ab + (size_t)(i0 + row) * 512 + k0 + q * 8);
            async16(&Bs[idx * 8], Bb + (size_t)(c0 + row) * 512 + k0 + q * 8);
        }
        __syncthreads();
        bf16x8 af[4], bfr[4];
#pragma unroll
        for (int mi = 0; mi < 4; mi++)
            af[mi] = *(const bf16x8*)&As[(wi * 64 + mi * 16 + lq) * 32 + quad * 8];
#pragma unroll
        for (int ni = 0; ni < 4; ni++)
            bfr[ni] = *(const bf16x8*)&Bs[(wc * 64 + ni * 16 + lq) * 32 + quad * 8];
#pragma unroll
        for (int mi = 0; mi < 4; mi++)
#pragma unroll
            for (int ni = 0; ni < 4; ni++)
                acc[mi][ni] = __builtin_amdgcn_mfma_f32_16x16x32_bf16(af[mi], bfr[ni], acc[mi][ni], 0, 0, 0);
        __syncthreads();
    }
    // epilogue: go = g * o, standard layout [(i*512+n)*64 + h*8 + d]
#pragma unroll
    for (int mi = 0; mi < 4; mi++)
#pragma unroll
        for (int ni = 0; ni < 4; ni++)
#pragma unroll
            for (int rr = 0; rr < 4; rr++) {
                int ii = i0 + wi * 64 + mi * 16 + quad * 4 + rr;
                int c  = c0 + wc * 64 + ni * 16 + lq;
                size_t off = ((size_t)ii * 512 + (c >> 3)) * 64 + h * 8 + (c & 7);
                float gv = b2f(gB[off]);
                go[off] = f2b(acc[mi][ni][rr] * gv);
            }
}

// ---------------------------------------------------------------------------
// K5: out = go @ W_out.T (fp32 out).  wave per row; W_out rows in regs.
// ---------------------------------------------------------------------------
__global__ __launch_bounds__(256) void k5_out(
    const unsigned short* __restrict__ go, const float* __restrict__ Wo, float* __restrict__ out)
{
    __shared__ float grow[4][64];
    const int t = threadIdx.x, w = t >> 6, lane = t & 63;
    float wo[64];
#pragma unroll
    for (int q = 0; q < 16; q++) {
        float4 a = *(const float4*)&Wo[lane * 64 + q * 4];
        wo[4*q+0]=a.x; wo[4*q+1]=a.y; wo[4*q+2]=a.z; wo[4*q+3]=a.w;
    }
    const int nw = gridDim.x * 4;
    for (int row = blockIdx.x * 4 + w; row < 262144; row += nw) {
        grow[w][lane] = b2f(go[(size_t)row * 64 + lane]);
        float acc = 0.f;
#pragma unroll
        for (int q = 0; q < 16; q++) {
            float4 gg = *(float4*)&grow[w][q * 4];  // wave-uniform broadcast
            acc += gg.x*wo[4*q] + gg.y*wo[4*q+1] + gg.z*wo[4*q+2] + gg.w*wo[4*q+3];
        }
        out[(size_t)row * 64 + lane] = acc;
    }
}

extern "C" void kernel_launch(void* const* d_in, const int* in_sizes, int n_in,
                              void* d_out, int out_size, void* d_ws, size_t ws_size,
                              hipStream_t stream)
{
    (void)in_sizes; (void)n_in; (void)out_size; (void)ws_size;
    const float* m    = (const float*)d_in[0];
    const float* z    = (const float*)d_in[1];
    const float* lnmw = (const float*)d_in[2];
    const float* lnmb = (const float*)d_in[3];
    const float* lnzw = (const float*)d_in[4];
    const float* lnzb = (const float*)d_in[5];
    const float* Wv   = (const float*)d_in[6];
    const float* Wb   = (const float*)d_in[7];
    const float* Wg   = (const float*)d_in[8];
    const float* Wo   = (const float*)d_in[9];
    float* out = (float*)d_out;
    char* ws = (char*)d_ws;

    unsigned short* vT = (unsigned short*)(ws);              // 8*4096*512*2  = 32 MiB
    unsigned short* wp = (unsigned short*)(ws + 33554432);   // 8*512*512*2   =  4 MiB
    unsigned short* gB = (unsigned short*)(ws + 37748736);   // 512*512*64*2  = 32 MiB
    float*          bL = (float*)(ws + 71303168);            // 512*512*8*4   =  8 MiB
    unsigned short* go = (unsigned short*)(ws + 79691776);   // 512*512*64*2  = 32 MiB

    k1_ln_vg  <<<dim3(512, 16), 256, 0, stream>>>(m, lnmw, lnmb, Wv, Wg, vT, gB);
    k2_ln_b   <<<dim3(1024),    256, 0, stream>>>(z, lnzw, lnzb, Wb, bL);
    k3_softmax<<<dim3(512),     256, 0, stream>>>(bL, wp);
    k4_einsum <<<dim3(32, 4, 8),256, 0, stream>>>(wp, vT, gB, go);
    k5_out    <<<dim3(2048),    256, 0, stream>>>(go, Wo, out);
}

// Round 2
// 447.885 us; speedup vs baseline: 1.3728x; 1.1351x over previous
//
#include <hip/hip_runtime.h>

typedef __bf16 bf16x8 __attribute__((ext_vector_type(8)));
typedef float  f32x4  __attribute__((ext_vector_type(4)));
typedef unsigned short u16x8 __attribute__((ext_vector_type(8)));

__device__ __forceinline__ float b2f(unsigned short u) {
    unsigned int x = ((unsigned int)u) << 16;
    float f; __builtin_memcpy(&f, &x, 4); return f;
}
__device__ __forceinline__ unsigned short f2b(float f) {
    unsigned int x; __builtin_memcpy(&x, &f, 4);
    unsigned int r = (x + 0x7FFFu + ((x >> 16) & 1u)) >> 16;
    return (unsigned short)r;
}
__device__ __forceinline__ void async16(void* lds, const void* g) {
    __builtin_amdgcn_global_load_lds((const __attribute__((address_space(1))) void*)g,
                                     (__attribute__((address_space(3))) void*)lds, 16, 0, 0);
}

// ---------------------------------------------------------------------------
// K0: pre-convert Wv,Wg (f32 64x64 each) -> bf16, K-tiled layout
// Wp[kchunk][col][u] : kchunk=0..7 (k = kchunk*8+u), col = 0..127 (0-63 Wv, 64-127 Wg)
// 8192 elems; one thread each.
// ---------------------------------------------------------------------------
__global__ __launch_bounds__(256) void k0_wcvt(
    const float* __restrict__ Wv, const float* __restrict__ Wg, unsigned short* __restrict__ Wp)
{
    const int idx = blockIdx.x * 256 + threadIdx.x;     // 0..8191
    const int cg = idx >> 10, col = (idx >> 3) & 127, u = idx & 7;
    const int k = cg * 8 + u;
    const float v = (col < 64) ? Wv[col * 64 + k] : Wg[(col - 64) * 64 + k];
    Wp[idx] = f2b(v);
}

// ---------------------------------------------------------------------------
// K1: LN(m) -> v = mhat@Wv.T (bf16, vT[h][c=n*8+d][j]) ; g = sigmoid(mhat@Wg.T)
// block = (n, 32-row s-chunk); 4 waves.
// Phase 1: cooperative LN of 32 rows -> bf16 mhb in LDS (K-tiled [8][32][8]).
// Phase 2: MFMA 16x16x32: wave w owns output cols [w*32, w*32+32) of the
//          32x128 (v||g) product; weights staged in LDS via global_load_lds.
// Epilogue: stage v,g fp32 in LDS; coalesced u16x8 global writes (unchanged layouts).
// ---------------------------------------------------------------------------
__global__ __launch_bounds__(256) void k1_ln_vg(
    const float* __restrict__ m, const float* __restrict__ lnw, const float* __restrict__ lnb,
    const unsigned short* __restrict__ Wp,
    unsigned short* __restrict__ vT, unsigned short* __restrict__ gB)
{
    __shared__ __align__(16) unsigned short Wl[8192];   // [8][128][8] bf16, 16 KB
    __shared__ __align__(16) unsigned short mhb[2048];  // [8][32][8]  bf16,  4 KB
    __shared__ float vstage[32][65];
    __shared__ float gstage[32][65];
    const int t = threadIdx.x, w = t >> 6, lane = t & 63;
    const int n = blockIdx.x, s0 = blockIdx.y * 32;

    // stage weights (16 KB, L2-hot): 1024 chunks of 16 B, 4 per thread
#pragma unroll
    for (int r = 0; r < 4; r++)
        async16(&Wl[(r * 256 + t) * 8], Wp + (size_t)(r * 256 + t) * 8);

    // ---- phase 1: LN. thread = (row rl = t>>3 in 0..31, 8-col chunk cg = t&7) ----
    const int rl = t >> 3, cg = t & 7, c8 = cg * 8;
    {
        const int s = s0 + rl;
        const float* src = &m[((size_t)s * 512 + n) * 64 + c8];
        float4 x0 = *(const float4*)src;
        float4 x1 = *(const float4*)(src + 4);
        float sum = x0.x+x0.y+x0.z+x0.w + x1.x+x1.y+x1.z+x1.w;
        float sq  = x0.x*x0.x+x0.y*x0.y+x0.z*x0.z+x0.w*x0.w
                  + x1.x*x1.x+x1.y*x1.y+x1.z*x1.z+x1.w*x1.w;
#pragma unroll
        for (int msk = 4; msk; msk >>= 1) { sum += __shfl_xor(sum, msk); sq += __shfl_xor(sq, msk); }
        float mu  = sum * (1.f / 64.f);
        float var = sq * (1.f / 64.f) - mu * mu;
        float rs  = rsqrtf(var + 1e-5f);
        float4 lw0 = *(const float4*)&lnw[c8], lw1 = *(const float4*)&lnw[c8 + 4];
        float4 lb0 = *(const float4*)&lnb[c8], lb1 = *(const float4*)&lnb[c8 + 4];
        u16x8 hb;
        hb[0] = f2b((x0.x - mu) * rs * lw0.x + lb0.x);
        hb[1] = f2b((x0.y - mu) * rs * lw0.y + lb0.y);
        hb[2] = f2b((x0.z - mu) * rs * lw0.z + lb0.z);
        hb[3] = f2b((x0.w - mu) * rs * lw0.w + lb0.w);
        hb[4] = f2b((x1.x - mu) * rs * lw1.x + lb1.x);
        hb[5] = f2b((x1.y - mu) * rs * lw1.y + lb1.y);
        hb[6] = f2b((x1.z - mu) * rs * lw1.z + lb1.z);
        hb[7] = f2b((x1.w - mu) * rs * lw1.w + lb1.w);
        *(u16x8*)&mhb[(cg * 32 + rl) * 8] = hb;   // K-tiled: chunk cg, row rl
    }
    __syncthreads();   // drains global_load_lds (vmcnt) + LDS writes

    // ---- phase 2: MFMA. wave w -> cols [w*32, w*32+32) ----
    const int quad = lane >> 4, lq = lane & 15;
    const int colbase = w * 32;
    f32x4 zero = {0.f, 0.f, 0.f, 0.f};
    f32x4 acc[2][2] = {{zero, zero}, {zero, zero}};
    bf16x8 af[2][2], bfr[2][2];
#pragma unroll
    for (int kk = 0; kk < 2; kk++) {
        const int ch = kk * 4 + quad;   // k-chunk index: k = ch*8 .. ch*8+7
#pragma unroll
        for (int mi = 0; mi < 2; mi++)
            af[mi][kk] = *(const bf16x8*)&mhb[(ch * 32 + mi * 16 + lq) * 8];
#pragma unroll
        for (int ni = 0; ni < 2; ni++)
            bfr[ni][kk] = *(const bf16x8*)&Wl[(ch * 128 + colbase + ni * 16 + lq) * 8];
    }
#pragma unroll
    for (int mi = 0; mi < 2; mi++)
#pragma unroll
        for (int ni = 0; ni < 2; ni++)
#pragma unroll
            for (int kk = 0; kk < 2; kk++)
                acc[mi][ni] = __builtin_amdgcn_mfma_f32_16x16x32_bf16(af[mi][kk], bfr[ni][kk], acc[mi][ni], 0, 0, 0);

    // ---- stage results: C[row][col], row=(mi*16+quad*4+rr), col=(colbase+ni*16+lq)
    if (w < 2) {
#pragma unroll
        for (int mi = 0; mi < 2; mi++)
#pragma unroll
            for (int ni = 0; ni < 2; ni++)
#pragma unroll
                for (int rr = 0; rr < 4; rr++)
                    vstage[mi * 16 + quad * 4 + rr][colbase + ni * 16 + lq] = acc[mi][ni][rr];
    } else {
#pragma unroll
        for (int mi = 0; mi < 2; mi++)
#pragma unroll
            for (int ni = 0; ni < 2; ni++)
#pragma unroll
                for (int rr = 0; rr < 4; rr++) {
                    float gg = 1.f / (1.f + __expf(-acc[mi][ni][rr]));
                    gstage[mi * 16 + quad * 4 + rr][colbase - 64 + ni * 16 + lq] = gg;
                }
    }
    __syncthreads();

    // ---- vT transpose write: thread t -> (h=t>>5, d=(t>>2)&7, jc=t&3) ----
    {
        const int h = t >> 5, d = (t >> 2) & 7, jc = t & 3;
        u16x8 pk;
#pragma unroll
        for (int u = 0; u < 8; u++) pk[u] = f2b(vstage[jc * 8 + u][h * 8 + d]);
        size_t off = (size_t)h * 2097152 + (size_t)(n * 8 + d) * 512 + (size_t)(s0 + jc * 8);
        *(u16x8*)(vT + off) = pk;
    }
    // ---- gB write: thread t -> (row rl, 8-col chunk c8), fully coalesced ----
    {
        u16x8 gk;
#pragma unroll
        for (int u = 0; u < 8; u++) gk[u] = f2b(gstage[rl][c8 + u]);
        *(u16x8*)(gB + ((size_t)(s0 + rl) * 512 + n) * 64 + c8) = gk;
    }
}

// ---------------------------------------------------------------------------
// K2: LN(z) row (128) -> logits b[i][j][h] fp32.  wave per row; W_b in regs
// lane = (h = lane&7, cg = lane>>3): partial dot over 16 c's, xor-reduce 8/16/32.
// ---------------------------------------------------------------------------
__global__ __launch_bounds__(256) void k2_ln_b(
    const float* __restrict__ z, const float* __restrict__ lnw, const float* __restrict__ lnb,
    const float* __restrict__ Wb, float* __restrict__ bL)
{
    __shared__ float zrow[4][132];
    const int t = threadIdx.x, w = t >> 6, lane = t & 63;
    const int h = lane & 7, cg = lane >> 3;
    float wb[16];
#pragma unroll
    for (int q = 0; q < 4; q++) {
        float4 a = *(const float4*)&Wb[h * 128 + cg * 16 + q * 4];
        wb[4*q+0]=a.x; wb[4*q+1]=a.y; wb[4*q+2]=a.z; wb[4*q+3]=a.w;
    }
    const float lw0 = lnw[lane], lw1 = lnw[64 + lane];
    const float lb0 = lnb[lane], lb1 = lnb[64 + lane];
    const int nw = gridDim.x * 4;
    for (int row = blockIdx.x * 4 + w; row < 262144; row += nw) {
        float x0 = z[(size_t)row * 128 + lane];
        float x1 = z[(size_t)row * 128 + 64 + lane];
        float sum = x0 + x1, sq = x0 * x0 + x1 * x1;
#pragma unroll
        for (int msk = 32; msk; msk >>= 1) { sum += __shfl_xor(sum, msk); sq += __shfl_xor(sq, msk); }
        float mu = sum * (1.f / 128.f);
        float var = sq * (1.f / 128.f) - mu * mu;
        float rs = rsqrtf(var + 1e-5f);
        zrow[w][lane]      = (x0 - mu) * rs * lw0 + lb0;
        zrow[w][64 + lane] = (x1 - mu) * rs * lw1 + lb1;
        float acc = 0.f;
#pragma unroll
        for (int q = 0; q < 4; q++) {
            float4 zz = *(float4*)&zrow[w][cg * 16 + q * 4];
            acc += zz.x*wb[4*q] + zz.y*wb[4*q+1] + zz.z*wb[4*q+2] + zz.w*wb[4*q+3];
        }
#pragma unroll
        for (int msk = 8; msk < 64; msk <<= 1) acc += __shfl_xor(acc, msk);
        if (lane < 8) bL[(size_t)row * 8 + lane] = acc;
    }
}

// ---------------------------------------------------------------------------
// K3: softmax over j per (i,h); reads b[i][j][h], writes w bf16 planar wp[h][i][j].
// block per i; 32-thread group per h.
// ---------------------------------------------------------------------------
__global__ __launch_bounds__(256) void k3_softmax(
    const float* __restrict__ bL, unsigned short* __restrict__ wp)
{
    __shared__ float bl[8][520];
    const int t = threadIdx.x;
    const int i = blockIdx.x;
    const float* src = bL + (size_t)i * 4096;
#pragma unroll
    for (int q = 0; q < 4; q++) {
        float4 a = *(const float4*)&src[q * 1024 + t * 4];
        int idx = q * 1024 + t * 4;
        bl[(idx+0)&7][(idx+0)>>3] = a.x;
        bl[(idx+1)&7][(idx+1)>>3] = a.y;
        bl[(idx+2)&7][(idx+2)>>3] = a.z;
        bl[(idx+3)&7][(idx+3)>>3] = a.w;
    }
    __syncthreads();
    const int h = t >> 5, l32 = t & 31;
    float vals[16];
    float mx = -1e30f;
#pragma unroll
    for (int jj = 0; jj < 16; jj++) { vals[jj] = bl[h][l32 + 32 * jj]; mx = fmaxf(mx, vals[jj]); }
#pragma unroll
    for (int msk = 1; msk < 32; msk <<= 1) mx = fmaxf(mx, __shfl_xor(mx, msk, 32));
    float s = 0.f;
#pragma unroll
    for (int jj = 0; jj < 16; jj++) { vals[jj] = __expf(vals[jj] - mx); s += vals[jj]; }
#pragma unroll
    for (int msk = 1; msk < 32; msk <<= 1) s += __shfl_xor(s, msk, 32);
    const float inv = 1.f / s;
    unsigned short* dst = wp + (size_t)h * 262144 + (size_t)i * 512;
#pragma unroll
    for (int jj = 0; jj < 16; jj++) dst[l32 + 32 * jj] = f2b(vals[jj] * inv);
}

// ---------------------------------------------------------------------------
// K4: per-head GEMM o_h[i][c] = w_h[i][:] @ vT_h[c][:]^T  (K=j=512), bf16 MFMA
// 128x128 tile, 4 waves, 16x16x32 frags; epilogue fuses g-gate, writes go bf16.
// ---------------------------------------------------------------------------
__global__ __launch_bounds__(256) void k4_einsum(
    const unsigned short* __restrict__ wp, const unsigned short* __restrict__ vT,
    const unsigned short* __restrict__ gB, unsigned short* __restrict__ go)
{
    __shared__ __align__(16) unsigned short As[128 * 32];
    __shared__ __align__(16) unsigned short Bs[128 * 32];
    const int t = threadIdx.x;
    const int c0 = blockIdx.x * 128, i0 = blockIdx.y * 128, h = blockIdx.z;
    const unsigned short* Ab = wp + (size_t)h * 262144;
    const unsigned short* Bb = vT + (size_t)h * 2097152;
    const int w = t >> 6, lane = t & 63, quad = lane >> 4, lq = lane & 15;
    const int wi = w >> 1, wc = w & 1;

    f32x4 zero = {0.f, 0.f, 0.f, 0.f};
    f32x4 acc[4][4];
#pragma unroll
    for (int mi = 0; mi < 4; mi++)
#pragma unroll
        for (int ni = 0; ni < 4; ni++) acc[mi][ni] = zero;

    for (int k0 = 0; k0 < 512; k0 += 32) {
#pragma unroll
        for (int r = 0; r < 2; r++) {
            int idx = r * 256 + t;
            int row = idx >> 2, q = idx & 3;
            async16(&As[idx * 8], Ab + (size_t)(i0 + row) * 512 + k0 + q * 8);
            async16(&Bs[idx * 8], Bb + (size_t)(c0 + row) * 512 + k0 + q * 8);
        }
        __syncthreads();
        bf16x8 af[4], bfr[4];
#pragma unroll
        for (int mi = 0; mi < 4; mi++)
            af[mi] = *(const bf16x8*)&As[(wi * 64 + mi * 16 + lq) * 32 + quad * 8];
#pragma unroll
        for (int ni = 0; ni < 4; ni++)
            bfr[ni] = *(const bf16x8*)&Bs[(wc * 64 + ni * 16 + lq) * 32 + quad * 8];
#pragma unroll
        for (int mi = 0; mi < 4; mi++)
#pragma unroll
            for (int ni = 0; ni < 4; ni++)
                acc[mi][ni] = __builtin_amdgcn_mfma_f32_16x16x32_bf16(af[mi], bfr[ni], acc[mi][ni], 0, 0, 0);
        __syncthreads();
    }
    // epilogue: go = g * o, standard layout [(i*512+n)*64 + h*8 + d]
#pragma unroll
    for (int mi = 0; mi < 4; mi++)
#pragma unroll
        for (int ni = 0; ni < 4; ni++)
#pragma unroll
            for (int rr = 0; rr < 4; rr++) {
                int ii = i0 + wi * 64 + mi * 16 + quad * 4 + rr;
                int c  = c0 + wc * 64 + ni * 16 + lq;
                size_t off = ((size_t)ii * 512 + (c >> 3)) * 64 + h * 8 + (c & 7);
                float gv = b2f(gB[off]);
                go[off] = f2b(acc[mi][ni][rr] * gv);
            }
}

// ---------------------------------------------------------------------------
// K5: out = go @ W_out.T (fp32 out).  wave per row; W_out rows in regs.
// ---------------------------------------------------------------------------
__global__ __launch_bounds__(256) void k5_out(
    const unsigned short* __restrict__ go, const float* __restrict__ Wo, float* __restrict__ out)
{
    __shared__ float grow[4][64];
    const int t = threadIdx.x, w = t >> 6, lane = t & 63;
    float wo[64];
#pragma unroll
    for (int q = 0; q < 16; q++) {
        float4 a = *(const float4*)&Wo[lane * 64 + q * 4];
        wo[4*q+0]=a.x; wo[4*q+1]=a.y; wo[4*q+2]=a.z; wo[4*q+3]=a.w;
    }
    const int nw = gridDim.x * 4;
    for (int row = blockIdx.x * 4 + w; row < 262144; row += nw) {
        grow[w][lane] = b2f(go[(size_t)row * 64 + lane]);
        float acc = 0.f;
#pragma unroll
        for (int q = 0; q < 16; q++) {
            float4 gg = *(float4*)&grow[w][q * 4];  // wave-uniform broadcast
            acc += gg.x*wo[4*q] + gg.y*wo[4*q+1] + gg.z*wo[4*q+2] + gg.w*wo[4*q+3];
        }
        out[(size_t)row * 64 + lane] = acc;
    }
}

extern "C" void kernel_launch(void* const* d_in, const int* in_sizes, int n_in,
                              void* d_out, int out_size, void* d_ws, size_t ws_size,
                              hipStream_t stream)
{
    (void)in_sizes; (void)n_in; (void)out_size; (void)ws_size;
    const float* m    = (const float*)d_in[0];
    const float* z    = (const float*)d_in[1];
    const float* lnmw = (const float*)d_in[2];
    const float* lnmb = (const float*)d_in[3];
    const float* lnzw = (const float*)d_in[4];
    const float* lnzb = (const float*)d_in[5];
    const float* Wv   = (const float*)d_in[6];
    const float* Wb   = (const float*)d_in[7];
    const float* Wg   = (const float*)d_in[8];
    const float* Wo   = (const float*)d_in[9];
    float* out = (float*)d_out;
    char* ws = (char*)d_ws;

    unsigned short* vT = (unsigned short*)(ws);              // 8*4096*512*2  = 32 MiB
    unsigned short* wp = (unsigned short*)(ws + 33554432);   // 8*512*512*2   =  4 MiB
    unsigned short* gB = (unsigned short*)(ws + 37748736);   // 512*512*64*2  = 32 MiB
    float*          bL = (float*)(ws + 71303168);            // 512*512*8*4   =  8 MiB
    unsigned short* go = (unsigned short*)(ws + 79691776);   // 512*512*64*2  = 32 MiB
    // Wp (16 KB bf16 weights) lives in the wp region: wp is only written by k3
    // (after k1 has fully consumed Wp) — stream order makes this safe.
    unsigned short* Wp = wp;

    k0_wcvt   <<<dim3(32),      256, 0, stream>>>(Wv, Wg, Wp);
    k1_ln_vg  <<<dim3(512, 16), 256, 0, stream>>>(m, lnmw, lnmb, Wp, vT, gB);
    k2_ln_b   <<<dim3(1024),    256, 0, stream>>>(z, lnzw, lnzb, Wb, bL);
    k3_softmax<<<dim3(512),     256, 0, stream>>>(bL, wp);
    k4_einsum <<<dim3(32, 4, 8),256, 0, stream>>>(wp, vT, gB, go);
    k5_out    <<<dim3(2048),    256, 0, stream>>>(go, Wo, out);
}

// Round 3
// 369.005 us; speedup vs baseline: 1.6662x; 1.2138x over previous
//
#include <hip/hip_runtime.h>

typedef __bf16 bf16x8 __attribute__((ext_vector_type(8)));
typedef float  f32x4  __attribute__((ext_vector_type(4)));
typedef unsigned short u16x8 __attribute__((ext_vector_type(8)));

__device__ __forceinline__ float b2f(unsigned short u) {
    unsigned int x = ((unsigned int)u) << 16;
    float f; __builtin_memcpy(&f, &x, 4); return f;
}
__device__ __forceinline__ unsigned short f2b(float f) {
    unsigned int x; __builtin_memcpy(&x, &f, 4);
    unsigned int r = (x + 0x7FFFu + ((x >> 16) & 1u)) >> 16;
    return (unsigned short)r;
}
__device__ __forceinline__ void async16(void* lds, const void* g) {
    __builtin_amdgcn_global_load_lds((const __attribute__((address_space(1))) void*)g,
                                     (__attribute__((address_space(3))) void*)lds, 16, 0, 0);
}

// ---------------------------------------------------------------------------
// K0: pre-convert Wv,Wg (f32 64x64 each) -> bf16, K-tiled layout
// Wp[kchunk][col][u] : kchunk=0..7 (k = kchunk*8+u), col = 0..127 (0-63 Wv, 64-127 Wg)
// ---------------------------------------------------------------------------
__global__ __launch_bounds__(256) void k0_wcvt(
    const float* __restrict__ Wv, const float* __restrict__ Wg, unsigned short* __restrict__ Wp)
{
    const int idx = blockIdx.x * 256 + threadIdx.x;     // 0..8191
    const int cg = idx >> 10, col = (idx >> 3) & 127, u = idx & 7;
    const int k = cg * 8 + u;
    const float v = (col < 64) ? Wv[col * 64 + k] : Wg[(col - 64) * 64 + k];
    Wp[idx] = f2b(v);
}

// ---------------------------------------------------------------------------
// K1: LN(m) -> v = mhat@Wv.T (bf16, vT[h][c=n*8+d][j]) ; g = sigmoid(mhat@Wg.T)
// block = (n, 32-row s-chunk); 4 waves.  MFMA 16x16x32 against LDS-staged weights.
// ---------------------------------------------------------------------------
__global__ __launch_bounds__(256) void k1_ln_vg(
    const float* __restrict__ m, const float* __restrict__ lnw, const float* __restrict__ lnb,
    const unsigned short* __restrict__ Wp,
    unsigned short* __restrict__ vT, unsigned short* __restrict__ gB)
{
    __shared__ __align__(16) unsigned short Wl[8192];   // [8][128][8] bf16, 16 KB
    __shared__ __align__(16) unsigned short mhb[2048];  // [8][32][8]  bf16,  4 KB
    __shared__ float vstage[32][65];
    __shared__ float gstage[32][65];
    const int t = threadIdx.x, w = t >> 6, lane = t & 63;
    const int n = blockIdx.x, s0 = blockIdx.y * 32;

#pragma unroll
    for (int r = 0; r < 4; r++)
        async16(&Wl[(r * 256 + t) * 8], Wp + (size_t)(r * 256 + t) * 8);

    // ---- phase 1: LN. thread = (row rl = t>>3 in 0..31, 8-col chunk cg = t&7) ----
    const int rl = t >> 3, cg = t & 7, c8 = cg * 8;
    {
        const int s = s0 + rl;
        const float* src = &m[((size_t)s * 512 + n) * 64 + c8];
        float4 x0 = *(const float4*)src;
        float4 x1 = *(const float4*)(src + 4);
        float sum = x0.x+x0.y+x0.z+x0.w + x1.x+x1.y+x1.z+x1.w;
        float sq  = x0.x*x0.x+x0.y*x0.y+x0.z*x0.z+x0.w*x0.w
                  + x1.x*x1.x+x1.y*x1.y+x1.z*x1.z+x1.w*x1.w;
#pragma unroll
        for (int msk = 4; msk; msk >>= 1) { sum += __shfl_xor(sum, msk); sq += __shfl_xor(sq, msk); }
        float mu  = sum * (1.f / 64.f);
        float var = sq * (1.f / 64.f) - mu * mu;
        float rs  = rsqrtf(var + 1e-5f);
        float4 lw0 = *(const float4*)&lnw[c8], lw1 = *(const float4*)&lnw[c8 + 4];
        float4 lb0 = *(const float4*)&lnb[c8], lb1 = *(const float4*)&lnb[c8 + 4];
        u16x8 hb;
        hb[0] = f2b((x0.x - mu) * rs * lw0.x + lb0.x);
        hb[1] = f2b((x0.y - mu) * rs * lw0.y + lb0.y);
        hb[2] = f2b((x0.z - mu) * rs * lw0.z + lb0.z);
        hb[3] = f2b((x0.w - mu) * rs * lw0.w + lb0.w);
        hb[4] = f2b((x1.x - mu) * rs * lw1.x + lb1.x);
        hb[5] = f2b((x1.y - mu) * rs * lw1.y + lb1.y);
        hb[6] = f2b((x1.z - mu) * rs * lw1.z + lb1.z);
        hb[7] = f2b((x1.w - mu) * rs * lw1.w + lb1.w);
        *(u16x8*)&mhb[(cg * 32 + rl) * 8] = hb;   // K-tiled: chunk cg, row rl
    }
    __syncthreads();   // drains global_load_lds (vmcnt) + LDS writes

    // ---- phase 2: MFMA. wave w -> cols [w*32, w*32+32) ----
    const int quad = lane >> 4, lq = lane & 15;
    const int colbase = w * 32;
    f32x4 zero = {0.f, 0.f, 0.f, 0.f};
    f32x4 acc[2][2] = {{zero, zero}, {zero, zero}};
    bf16x8 af[2][2], bfr[2][2];
#pragma unroll
    for (int kk = 0; kk < 2; kk++) {
        const int ch = kk * 4 + quad;   // k-chunk index: k = ch*8 .. ch*8+7
#pragma unroll
        for (int mi = 0; mi < 2; mi++)
            af[mi][kk] = *(const bf16x8*)&mhb[(ch * 32 + mi * 16 + lq) * 8];
#pragma unroll
        for (int ni = 0; ni < 2; ni++)
            bfr[ni][kk] = *(const bf16x8*)&Wl[(ch * 128 + colbase + ni * 16 + lq) * 8];
    }
#pragma unroll
    for (int mi = 0; mi < 2; mi++)
#pragma unroll
        for (int ni = 0; ni < 2; ni++)
#pragma unroll
            for (int kk = 0; kk < 2; kk++)
                acc[mi][ni] = __builtin_amdgcn_mfma_f32_16x16x32_bf16(af[mi][kk], bfr[ni][kk], acc[mi][ni], 0, 0, 0);

    if (w < 2) {
#pragma unroll
        for (int mi = 0; mi < 2; mi++)
#pragma unroll
            for (int ni = 0; ni < 2; ni++)
#pragma unroll
                for (int rr = 0; rr < 4; rr++)
                    vstage[mi * 16 + quad * 4 + rr][colbase + ni * 16 + lq] = acc[mi][ni][rr];
    } else {
#pragma unroll
        for (int mi = 0; mi < 2; mi++)
#pragma unroll
            for (int ni = 0; ni < 2; ni++)
#pragma unroll
                for (int rr = 0; rr < 4; rr++) {
                    float gg = 1.f / (1.f + __expf(-acc[mi][ni][rr]));
                    gstage[mi * 16 + quad * 4 + rr][colbase - 64 + ni * 16 + lq] = gg;
                }
    }
    __syncthreads();

    // ---- vT transpose write ----
    {
        const int h = t >> 5, d = (t >> 2) & 7, jc = t & 3;
        u16x8 pk;
#pragma unroll
        for (int u = 0; u < 8; u++) pk[u] = f2b(vstage[jc * 8 + u][h * 8 + d]);
        size_t off = (size_t)h * 2097152 + (size_t)(n * 8 + d) * 512 + (size_t)(s0 + jc * 8);
        *(u16x8*)(vT + off) = pk;
    }
    // ---- gB write ----
    {
        u16x8 gk;
#pragma unroll
        for (int u = 0; u < 8; u++) gk[u] = f2b(gstage[rl][c8 + u]);
        *(u16x8*)(gB + ((size_t)(s0 + rl) * 512 + n) * 64 + c8) = gk;
    }
}

// ---------------------------------------------------------------------------
// K2: LN(z) row (128) -> logits b[i][j][h] fp32.
// One-shot: 4 lanes per row (qt = quarter), 8 independent float4 loads each,
// 2-shuffle mean/var, dot vs Wb staged in LDS [h][128], 2-shuffle combine,
// float2 coalesced store. No grid-stride loop -> latency hidden by TLP.
// ---------------------------------------------------------------------------
__global__ __launch_bounds__(256) void k2_ln_b(
    const float* __restrict__ z, const float* __restrict__ lnw, const float* __restrict__ lnb,
    const float* __restrict__ Wb, float* __restrict__ bL)
{
    __shared__ float swb[1024];   // [h][128] == Wb layout
    __shared__ float sw[128], sb[128];
    const int t = threadIdx.x;
    const int gtid = blockIdx.x * 256 + t;
    const int row = gtid >> 2, qt = gtid & 3;

    // issue z loads first (independent of LDS staging)
    const float* src = z + (size_t)row * 128;
    float4 x[8];
#pragma unroll
    for (int q = 0; q < 8; q++)
        x[q] = *(const float4*)&src[q * 16 + qt * 4];   // lanes qt0-3 -> 64B contiguous

    *(float4*)&swb[t * 4] = *(const float4*)&Wb[t * 4];
    if (t < 32)      *(float4*)&sw[t * 4] = *(const float4*)&lnw[t * 4];
    else if (t < 64) *(float4*)&sb[(t - 32) * 4] = *(const float4*)&lnb[(t - 32) * 4];
    __syncthreads();

    float sum = 0.f, sq = 0.f;
#pragma unroll
    for (int q = 0; q < 8; q++) {
        sum += x[q].x + x[q].y + x[q].z + x[q].w;
        sq  += x[q].x*x[q].x + x[q].y*x[q].y + x[q].z*x[q].z + x[q].w*x[q].w;
    }
    sum += __shfl_xor(sum, 1); sq += __shfl_xor(sq, 1);
    sum += __shfl_xor(sum, 2); sq += __shfl_xor(sq, 2);
    const float mu  = sum * (1.f / 128.f);
    const float var = sq * (1.f / 128.f) - mu * mu;
    const float rs  = rsqrtf(var + 1e-5f);

    float acc[8];
#pragma unroll
    for (int h = 0; h < 8; h++) acc[h] = 0.f;
#pragma unroll
    for (int q = 0; q < 8; q++) {
        const int c0 = q * 16 + qt * 4;
        const float4 lw = *(const float4*)&sw[c0];
        const float4 lb = *(const float4*)&sb[c0];
        const float zn0 = (x[q].x - mu) * rs * lw.x + lb.x;
        const float zn1 = (x[q].y - mu) * rs * lw.y + lb.y;
        const float zn2 = (x[q].z - mu) * rs * lw.z + lb.z;
        const float zn3 = (x[q].w - mu) * rs * lw.w + lb.w;
#pragma unroll
        for (int h = 0; h < 8; h++) {
            const float4 wv = *(const float4*)&swb[h * 128 + c0];  // bcast + 4-lane contig
            acc[h] += zn0 * wv.x + zn1 * wv.y + zn2 * wv.z + zn3 * wv.w;
        }
    }
#pragma unroll
    for (int h = 0; h < 8; h++) { acc[h] += __shfl_xor(acc[h], 1); acc[h] += __shfl_xor(acc[h], 2); }
    float2 o; o.x = acc[qt * 2]; o.y = acc[qt * 2 + 1];
    *(float2*)&bL[(size_t)row * 8 + qt * 2] = o;
}

// ---------------------------------------------------------------------------
// K3: softmax over j per (i,h); reads b[i][j][h], writes w bf16 planar wp[h][i][j].
// ---------------------------------------------------------------------------
__global__ __launch_bounds__(256) void k3_softmax(
    const float* __restrict__ bL, unsigned short* __restrict__ wp)
{
    __shared__ float bl[8][520];
    const int t = threadIdx.x;
    const int i = blockIdx.x;
    const float* src = bL + (size_t)i * 4096;
#pragma unroll
    for (int q = 0; q < 4; q++) {
        float4 a = *(const float4*)&src[q * 1024 + t * 4];
        int idx = q * 1024 + t * 4;
        bl[(idx+0)&7][(idx+0)>>3] = a.x;
        bl[(idx+1)&7][(idx+1)>>3] = a.y;
        bl[(idx+2)&7][(idx+2)>>3] = a.z;
        bl[(idx+3)&7][(idx+3)>>3] = a.w;
    }
    __syncthreads();
    const int h = t >> 5, l32 = t & 31;
    float vals[16];
    float mx = -1e30f;
#pragma unroll
    for (int jj = 0; jj < 16; jj++) { vals[jj] = bl[h][l32 + 32 * jj]; mx = fmaxf(mx, vals[jj]); }
#pragma unroll
    for (int msk = 1; msk < 32; msk <<= 1) mx = fmaxf(mx, __shfl_xor(mx, msk, 32));
    float s = 0.f;
#pragma unroll
    for (int jj = 0; jj < 16; jj++) { vals[jj] = __expf(vals[jj] - mx); s += vals[jj]; }
#pragma unroll
    for (int msk = 1; msk < 32; msk <<= 1) s += __shfl_xor(s, msk, 32);
    const float inv = 1.f / s;
    unsigned short* dst = wp + (size_t)h * 262144 + (size_t)i * 512;
#pragma unroll
    for (int jj = 0; jj < 16; jj++) dst[l32 + 32 * jj] = f2b(vals[jj] * inv);
}

// ---------------------------------------------------------------------------
// K4: per-head GEMM o_h[i][c] = w_h[i][:] @ vT_h[c][:]^T  (K=j=512), bf16 MFMA
// ---------------------------------------------------------------------------
__global__ __launch_bounds__(256) void k4_einsum(
    const unsigned short* __restrict__ wp, const unsigned short* __restrict__ vT,
    const unsigned short* __restrict__ gB, unsigned short* __restrict__ go)
{
    __shared__ __align__(16) unsigned short As[128 * 32];
    __shared__ __align__(16) unsigned short Bs[128 * 32];
    const int t = threadIdx.x;
    const int c0 = blockIdx.x * 128, i0 = blockIdx.y * 128, h = blockIdx.z;
    const unsigned short* Ab = wp + (size_t)h * 262144;
    const unsigned short* Bb = vT + (size_t)h * 2097152;
    const int w = t >> 6, lane = t & 63, quad = lane >> 4, lq = lane & 15;
    const int wi = w >> 1, wc = w & 1;

    f32x4 zero = {0.f, 0.f, 0.f, 0.f};
    f32x4 acc[4][4];
#pragma unroll
    for (int mi = 0; mi < 4; mi++)
#pragma unroll
        for (int ni = 0; ni < 4; ni++) acc[mi][ni] = zero;

    for (int k0 = 0; k0 < 512; k0 += 32) {
#pragma unroll
        for (int r = 0; r < 2; r++) {
            int idx = r * 256 + t;
            int row = idx >> 2, q = idx & 3;
            async16(&As[idx * 8], Ab + (size_t)(i0 + row) * 512 + k0 + q * 8);
            async16(&Bs[idx * 8], Bb + (size_t)(c0 + row) * 512 + k0 + q * 8);
        }
        __syncthreads();
        bf16x8 af[4], bfr[4];
#pragma unroll
        for (int mi = 0; mi < 4; mi++)
            af[mi] = *(const bf16x8*)&As[(wi * 64 + mi * 16 + lq) * 32 + quad * 8];
#pragma unroll
        for (int ni = 0; ni < 4; ni++)
            bfr[ni] = *(const bf16x8*)&Bs[(wc * 64 + ni * 16 + lq) * 32 + quad * 8];
#pragma unroll
        for (int mi = 0; mi < 4; mi++)
#pragma unroll
            for (int ni = 0; ni < 4; ni++)
                acc[mi][ni] = __builtin_amdgcn_mfma_f32_16x16x32_bf16(af[mi], bfr[ni], acc[mi][ni], 0, 0, 0);
        __syncthreads();
    }
#pragma unroll
    for (int mi = 0; mi < 4; mi++)
#pragma unroll
        for (int ni = 0; ni < 4; ni++)
#pragma unroll
            for (int rr = 0; rr < 4; rr++) {
                int ii = i0 + wi * 64 + mi * 16 + quad * 4 + rr;
                int c  = c0 + wc * 64 + ni * 16 + lq;
                size_t off = ((size_t)ii * 512 + (c >> 3)) * 64 + h * 8 + (c & 7);
                float gv = b2f(gB[off]);
                go[off] = f2b(acc[mi][ni][rr] * gv);
            }
}

// ---------------------------------------------------------------------------
// K5: out = go @ W_out.T (fp32 out), bf16 MFMA with Wo hi+lo split (~fp32 acc).
// Block = 64 rows (4 waves x 16). A-frags loaded straight from go (bf16).
// Wo converted+staged per block: Bs[term][ch][col][8], 16 KB.
// ---------------------------------------------------------------------------
__global__ __launch_bounds__(256) void k5_out(
    const unsigned short* __restrict__ go, const float* __restrict__ Wo, float* __restrict__ out)
{
    __shared__ __align__(16) unsigned short Bs[8192];  // [2][8][64][8]
    const int t = threadIdx.x, w = t >> 6, lane = t & 63;
    const int quad = lane >> 4, lq = lane & 15;

    const int r0 = blockIdx.x * 64 + w * 16;
    const unsigned short* Ab = go + (size_t)r0 * 64;
    bf16x8 a[2];
#pragma unroll
    for (int kk = 0; kk < 2; kk++)
        a[kk] = *(const bf16x8*)&Ab[lq * 64 + (kk * 4 + quad) * 8];

#pragma unroll
    for (int r = 0; r < 2; r++) {
        const int idx = r * 256 + t;            // 0..511 = (ch, col)
        const int ch = idx >> 6, col = idx & 63;
        const float* srcw = &Wo[col * 64 + ch * 8];
        float4 w0 = *(const float4*)srcw;
        float4 w1 = *(const float4*)(srcw + 4);
        float v[8] = {w0.x, w0.y, w0.z, w0.w, w1.x, w1.y, w1.z, w1.w};
        u16x8 hi, lo;
#pragma unroll
        for (int u = 0; u < 8; u++) { hi[u] = f2b(v[u]); lo[u] = f2b(v[u] - b2f(hi[u])); }
        *(u16x8*)&Bs[(ch * 64 + col) * 8] = hi;
        *(u16x8*)&Bs[4096 + (ch * 64 + col) * 8] = lo;
    }
    __syncthreads();

    f32x4 zero = {0.f, 0.f, 0.f, 0.f};
#pragma unroll
    for (int ni = 0; ni < 4; ni++) {
        f32x4 acc = zero;
#pragma unroll
        for (int kk = 0; kk < 2; kk++) {
            const int ko = (kk * 4 + quad) * 64;
            bf16x8 bh = *(const bf16x8*)&Bs[(ko + ni * 16 + lq) * 8];
            bf16x8 bl = *(const bf16x8*)&Bs[4096 + (ko + ni * 16 + lq) * 8];
            acc = __builtin_amdgcn_mfma_f32_16x16x32_bf16(a[kk], bh, acc, 0, 0, 0);
            acc = __builtin_amdgcn_mfma_f32_16x16x32_bf16(a[kk], bl, acc, 0, 0, 0);
        }
#pragma unroll
        for (int rr = 0; rr < 4; rr++)
            out[(size_t)(r0 + quad * 4 + rr) * 64 + ni * 16 + lq] = acc[rr];
    }
}

extern "C" void kernel_launch(void* const* d_in, const int* in_sizes, int n_in,
                              void* d_out, int out_size, void* d_ws, size_t ws_size,
                              hipStream_t stream)
{
    (void)in_sizes; (void)n_in; (void)out_size; (void)ws_size;
    const float* m    = (const float*)d_in[0];
    const float* z    = (const float*)d_in[1];
    const float* lnmw = (const float*)d_in[2];
    const float* lnmb = (const float*)d_in[3];
    const float* lnzw = (const float*)d_in[4];
    const float* lnzb = (const float*)d_in[5];
    const float* Wv   = (const float*)d_in[6];
    const float* Wb   = (const float*)d_in[7];
    const float* Wg   = (const float*)d_in[8];
    const float* Wo   = (const float*)d_in[9];
    float* out = (float*)d_out;
    char* ws = (char*)d_ws;

    unsigned short* vT = (unsigned short*)(ws);              // 8*4096*512*2  = 32 MiB
    unsigned short* wp = (unsigned short*)(ws + 33554432);   // 8*512*512*2   =  4 MiB
    unsigned short* gB = (unsigned short*)(ws + 37748736);   // 512*512*64*2  = 32 MiB
    float*          bL = (float*)(ws + 71303168);            // 512*512*8*4   =  8 MiB
    unsigned short* go = (unsigned short*)(ws + 79691776);   // 512*512*64*2  = 32 MiB
    // Wp (16 KB bf16 weights) in wp region: wp is only written by k3, after k1
    // has fully consumed Wp — stream order makes this safe.
    unsigned short* Wp = wp;

    k0_wcvt   <<<dim3(32),      256, 0, stream>>>(Wv, Wg, Wp);
    k1_ln_vg  <<<dim3(512, 16), 256, 0, stream>>>(m, lnmw, lnmb, Wp, vT, gB);
    k2_ln_b   <<<dim3(4096),    256, 0, stream>>>(z, lnzw, lnzb, Wb, bL);
    k3_softmax<<<dim3(512),     256, 0, stream>>>(bL, wp);
    k4_einsum <<<dim3(32, 4, 8),256, 0, stream>>>(wp, vT, gB, go);
    k5_out    <<<dim3(4096),    256, 0, stream>>>(go, Wo, out);
}